// Round 1
// baseline (908.792 us; speedup 1.0000x reference)
//
#include <hip/hip_runtime.h>

#define NN 100000
#define NE 1600000
#define NG 256
#define NPB 32            // nodes per block-pass in layer kernel
#define LAYER_GRID 512

// ---------------- CSR build (by dst) ----------------
__global__ __launch_bounds__(256) void hist_kernel(const int* __restrict__ dst,
                                                   int* __restrict__ cnt) {
    int i = blockIdx.x * 256 + threadIdx.x;
    if (i < NE) atomicAdd(&cnt[dst[i]], 1);
}

__global__ __launch_bounds__(1024) void scan_kernel(const int* __restrict__ cnt,
                                                    int* __restrict__ rs,
                                                    int* __restrict__ cursor) {
    __shared__ int s[1024];
    const int C = (NN + 1023) / 1024;   // 98
    const int t = threadIdx.x;
    const int lo = t * C;
    const int hi = min(lo + C, NN);
    int sum = 0;
    for (int i = lo; i < hi; ++i) sum += cnt[i];
    s[t] = sum;
    __syncthreads();
    for (int off = 1; off < 1024; off <<= 1) {
        int v = (t >= off) ? s[t - off] : 0;
        __syncthreads();
        s[t] += v;
        __syncthreads();
    }
    int run = (t == 0) ? 0 : s[t - 1];
    for (int i = lo; i < hi; ++i) { rs[i] = run; cursor[i] = run; run += cnt[i]; }
    if (hi == NN) rs[NN] = run;   // tail threads hold the inclusive total; same value
}

__global__ __launch_bounds__(256) void fill_kernel(const int* __restrict__ src,
                                                   const int* __restrict__ dst,
                                                   int* __restrict__ cursor,
                                                   int* __restrict__ csr) {
    int i = blockIdx.x * 256 + threadIdx.x;
    if (i < NE) {
        int pos = atomicAdd(&cursor[dst[i]], 1);
        csr[pos] = src[i];
    }
}

// ---------------- fused GNN layer ----------------
// out = relu( h@Wa+ba  +  agg(h)@Wc+bc  +  (h@Wb+bb)*(h@Wd+bd) )
// Block: 512 thr = 8 waves; wave handles 4 nodes; lane = nj*16 + fg.
// LDS: 4 weight mats (64KB) + h/agg staging (16KB) = 80KB -> 2 blocks/CU.
__global__ __launch_bounds__(512, 4) void layer_kernel(
    const float* __restrict__ h_in, float* __restrict__ h_out,
    const int* __restrict__ csr, const int* __restrict__ rs,
    const float* __restrict__ Wa, const float* __restrict__ ba,
    const float* __restrict__ Wc, const float* __restrict__ bc,
    const float* __restrict__ Wb, const float* __restrict__ bb,
    const float* __restrict__ Wd, const float* __restrict__ bd)
{
    __shared__ float4 sWa[1024], sWc[1024], sWb[1024], sWd[1024];
    __shared__ __align__(16) float sh_h[NPB][64];
    __shared__ __align__(16) float sh_g[NPB][64];

    const int tid = threadIdx.x;
    for (int i = tid; i < 1024; i += 512) {
        sWa[i] = ((const float4*)Wa)[i];
        sWc[i] = ((const float4*)Wc)[i];
        sWb[i] = ((const float4*)Wb)[i];
        sWd[i] = ((const float4*)Wd)[i];
    }

    const int lane = tid & 63;
    const int wave = tid >> 6;
    const int nj   = lane >> 4;     // node within wave: 0..3
    const int fg   = lane & 15;     // feature group: 4 floats each
    const int slot = wave * 4 + nj; // 0..31

    const float4 bia  = ((const float4*)ba)[fg];
    const float4 bic  = ((const float4*)bc)[fg];
    const float4 bib  = ((const float4*)bb)[fg];
    const float4 bid_ = ((const float4*)bd)[fg];

    const int ngroups = (NN + NPB - 1) / NPB;
    for (int g = blockIdx.x; g < ngroups; g += gridDim.x) {
        const int node = g * NPB + slot;
        float4 h4 = make_float4(0.f, 0.f, 0.f, 0.f);
        float4 a4 = make_float4(0.f, 0.f, 0.f, 0.f);
        if (node < NN) {
            h4 = *(const float4*)(h_in + node * 64 + fg * 4);
            int e = rs[node];
            const int ee = rs[node + 1];
            for (; e < ee; ++e) {
                const int sN = csr[e];
                const float4 v = *(const float4*)(h_in + sN * 64 + fg * 4);
                a4.x += v.x; a4.y += v.y; a4.z += v.z; a4.w += v.w;
            }
        }
        __syncthreads();   // protect previous iteration's sh reads (and weight load, iter 0)
        *(float4*)(&sh_h[slot][fg * 4]) = h4;
        *(float4*)(&sh_g[slot][fg * 4]) = a4;
        __syncthreads();

        float4 accA = {0.f,0.f,0.f,0.f}, accC = {0.f,0.f,0.f,0.f};
        float4 accB = {0.f,0.f,0.f,0.f}, accD = {0.f,0.f,0.f,0.f};
        #pragma unroll 8
        for (int k = 0; k < 64; ++k) {
            const float hk = sh_h[slot][k];
            const float gk = sh_g[slot][k];
            const float4 wa = sWa[k * 16 + fg];
            const float4 wc = sWc[k * 16 + fg];
            const float4 wb = sWb[k * 16 + fg];
            const float4 wd = sWd[k * 16 + fg];
            accA.x = fmaf(hk, wa.x, accA.x); accA.y = fmaf(hk, wa.y, accA.y);
            accA.z = fmaf(hk, wa.z, accA.z); accA.w = fmaf(hk, wa.w, accA.w);
            accC.x = fmaf(gk, wc.x, accC.x); accC.y = fmaf(gk, wc.y, accC.y);
            accC.z = fmaf(gk, wc.z, accC.z); accC.w = fmaf(gk, wc.w, accC.w);
            accB.x = fmaf(hk, wb.x, accB.x); accB.y = fmaf(hk, wb.y, accB.y);
            accB.z = fmaf(hk, wb.z, accB.z); accB.w = fmaf(hk, wb.w, accB.w);
            accD.x = fmaf(hk, wd.x, accD.x); accD.y = fmaf(hk, wd.y, accD.y);
            accD.z = fmaf(hk, wd.z, accD.z); accD.w = fmaf(hk, wd.w, accD.w);
        }
        if (node < NN) {
            float4 o;
            o.x = fmaxf((accA.x + bia.x) + (accC.x + bic.x) + (accB.x + bib.x) * (accD.x + bid_.x), 0.f);
            o.y = fmaxf((accA.y + bia.y) + (accC.y + bic.y) + (accB.y + bib.y) * (accD.y + bid_.y), 0.f);
            o.z = fmaxf((accA.z + bia.z) + (accC.z + bic.z) + (accB.z + bib.z) * (accD.z + bid_.z), 0.f);
            o.w = fmaxf((accA.w + bia.w) + (accC.w + bic.w) + (accB.w + bib.w) * (accD.w + bid_.w), 0.f);
            *(float4*)(h_out + node * 64 + fg * 4) = o;
        }
    }
}

// ---------------- pool + MLP ----------------
__global__ __launch_bounds__(256) void pool_mlp_kernel(
    const float* __restrict__ h, const int* __restrict__ batch,
    const float* __restrict__ w1, const float* __restrict__ b1,
    const float* __restrict__ w2, const float* __restrict__ b2,
    float* __restrict__ out)
{
    const int g = blockIdx.x;
    const int t = threadIdx.x;
    int lo = 0, hi = NN;
    while (lo < hi) { int m = (lo + hi) >> 1; if (batch[m] < g) lo = m + 1; else hi = m; }
    const int start = lo;
    hi = NN;
    while (lo < hi) { int m = (lo + hi) >> 1; if (batch[m] < g + 1) lo = m + 1; else hi = m; }
    const int end = lo;

    const int f = t & 63, wsub = t >> 6;
    float sum = 0.f;
    for (int n = start + wsub; n < end; n += 4) sum += h[n * 64 + f];
    __shared__ float red[4][64];
    red[wsub][f] = sum;
    __syncthreads();
    __shared__ float pooled[64];
    if (t < 64) {
        float tot = red[0][t] + red[1][t] + red[2][t] + red[3][t];
        pooled[t] = tot / fmaxf((float)(end - start), 1.f);
    }
    __syncthreads();
    __shared__ float y10[10];
    if (t < 10) {
        float acc = b1[t];
        for (int k = 0; k < 64; ++k) acc = fmaf(pooled[k], w1[k * 10 + t], acc);
        y10[t] = acc;
    }
    __syncthreads();
    if (t == 0) {
        float acc = b2[0];
        for (int j = 0; j < 10; ++j) acc = fmaf(y10[j], w2[j], acc);
        out[g] = acc;
    }
}

extern "C" void kernel_launch(void* const* d_in, const int* in_sizes, int n_in,
                              void* d_out, int out_size, void* d_ws, size_t ws_size,
                              hipStream_t stream) {
    const float* x    = (const float*)d_in[0];
    const int* ei     = (const int*)d_in[1];
    const int* batch  = (const int*)d_in[2];
    const int* src    = ei;
    const int* dstv   = ei + NE;

    // workspace layout (bytes):
    //   hA: [0, 25.6M)   hB: [25.6M, 51.2M)   csr: [51.2M, 57.6M)   rs: [57.6M, +400004)
    //   cnt aliases hB+0, cursor aliases hB+512K (both dead before hB is first written)
    char* ws   = (char*)d_ws;
    float* hA  = (float*)(ws);
    float* hB  = (float*)(ws + 25600000);
    int* csr   = (int*)(ws + 51200000);
    int* rs    = (int*)(ws + 57600000);
    int* cnt   = (int*)hB;
    int* cursor = (int*)(ws + 25600000 + 524288);

    hipMemsetAsync(cnt, 0, NN * sizeof(int), stream);
    hist_kernel<<<(NE + 255) / 256, 256, 0, stream>>>(dstv, cnt);
    scan_kernel<<<1, 1024, 0, stream>>>(cnt, rs, cursor);
    fill_kernel<<<(NE + 255) / 256, 256, 0, stream>>>(src, dstv, cursor, csr);

    auto f = [&](int i) { return (const float*)d_in[i]; };
    // layer(h, fa=fc{l}1, conv, fb=fc{l}2, fc=fc{l}3)
    layer_kernel<<<LAYER_GRID, 512, 0, stream>>>(x, hA, csr, rs,
        f(5), f(6), f(3), f(4), f(7), f(8), f(9), f(10));
    layer_kernel<<<LAYER_GRID, 512, 0, stream>>>(hA, hB, csr, rs,
        f(13), f(14), f(11), f(12), f(15), f(16), f(17), f(18));
    layer_kernel<<<LAYER_GRID, 512, 0, stream>>>(hB, hA, csr, rs,
        f(21), f(22), f(19), f(20), f(23), f(24), f(25), f(26));

    pool_mlp_kernel<<<NG, 256, 0, stream>>>(hA, batch,
        f(27), f(28), f(29), f(30), (float*)d_out);
}

// Round 2
// 689.142 us; speedup vs baseline: 1.3187x; 1.3187x over previous
//
#include <hip/hip_runtime.h>

#define NN 100000
#define NE 1600000
#define NG 256
#define NPB 32            // nodes per block-pass in layer kernel
#define LAYER_GRID 512
#define SCHUNK 1024
#define SNBLK ((NN + SCHUNK - 1) / SCHUNK)   // 98

// ---------------- CSR build (by dst) ----------------
__global__ __launch_bounds__(256) void hist_kernel(const int* __restrict__ dst,
                                                   int* __restrict__ cnt) {
    int i = blockIdx.x * 256 + threadIdx.x;
    if (i < NE) atomicAdd(&cnt[dst[i]], 1);
}

// Pass 1: per-block (1024 counts) exclusive scan -> rs, block total -> bsum[b]
__global__ __launch_bounds__(256) void scan1_kernel(const int* __restrict__ cnt,
                                                    int* __restrict__ rs,
                                                    int* __restrict__ bsum) {
    __shared__ int s[256];
    const int b = blockIdx.x, t = threadIdx.x;
    const int idx = b * SCHUNK + t * 4;
    int4 v = {0, 0, 0, 0};
    if (idx + 3 < NN) v = *(const int4*)(cnt + idx);
    else {
        if (idx + 0 < NN) v.x = cnt[idx + 0];
        if (idx + 1 < NN) v.y = cnt[idx + 1];
        if (idx + 2 < NN) v.z = cnt[idx + 2];
        if (idx + 3 < NN) v.w = cnt[idx + 3];
    }
    s[t] = v.x + v.y + v.z + v.w;
    __syncthreads();
    for (int off = 1; off < 256; off <<= 1) {
        int u = (t >= off) ? s[t - off] : 0;
        __syncthreads();
        s[t] += u;
        __syncthreads();
    }
    int r0 = (t == 0) ? 0 : s[t - 1];
    int r1 = r0 + v.x, r2 = r1 + v.y, r3 = r2 + v.z;
    if (idx + 0 < NN) rs[idx + 0] = r0;
    if (idx + 1 < NN) rs[idx + 1] = r1;
    if (idx + 2 < NN) rs[idx + 2] = r2;
    if (idx + 3 < NN) rs[idx + 3] = r3;
    if (t == 255) bsum[b] = s[255];
}

// Pass 2: exclusive scan of the SNBLK block sums; also write grand total to rs[NN]
__global__ __launch_bounds__(128) void scan2_kernel(int* __restrict__ bsum,
                                                    int* __restrict__ rs) {
    __shared__ int s[128];
    const int t = threadIdx.x;
    int v = (t < SNBLK) ? bsum[t] : 0;
    s[t] = v;
    __syncthreads();
    for (int off = 1; off < 128; off <<= 1) {
        int u = (t >= off) ? s[t - off] : 0;
        __syncthreads();
        s[t] += u;
        __syncthreads();
    }
    if (t < SNBLK) bsum[t] = (t == 0) ? 0 : s[t - 1];
    if (t == 127) rs[NN] = s[127];
}

// Pass 3: add block offsets; mirror into cursor
__global__ __launch_bounds__(256) void scan3_kernel(int* __restrict__ rs,
                                                    const int* __restrict__ bsum,
                                                    int* __restrict__ cursor) {
    const int b = blockIdx.x, t = threadIdx.x;
    const int off = bsum[b];
    const int idx = b * SCHUNK + t * 4;
    if (idx + 3 < NN) {
        int4 v = *(const int4*)(rs + idx);
        v.x += off; v.y += off; v.z += off; v.w += off;
        *(int4*)(rs + idx) = v;
        *(int4*)(cursor + idx) = v;
    } else {
        for (int j = 0; j < 4; ++j)
            if (idx + j < NN) { int v = rs[idx + j] + off; rs[idx + j] = v; cursor[idx + j] = v; }
    }
}

__global__ __launch_bounds__(256) void fill_kernel(const int* __restrict__ src,
                                                   const int* __restrict__ dst,
                                                   int* __restrict__ cursor,
                                                   int* __restrict__ csr) {
    int i = blockIdx.x * 256 + threadIdx.x;
    if (i < NE) {
        int pos = atomicAdd(&cursor[dst[i]], 1);
        csr[pos] = src[i];
    }
}

// ---------------- fused GNN layer ----------------
// out = relu( h@Wa+ba  +  agg(h)@Wc+bc  +  (h@Wb+bb)*(h@Wd+bd) )
__global__ __launch_bounds__(512, 4) void layer_kernel(
    const float* __restrict__ h_in, float* __restrict__ h_out,
    const int* __restrict__ csr, const int* __restrict__ rs,
    const float* __restrict__ Wa, const float* __restrict__ ba,
    const float* __restrict__ Wc, const float* __restrict__ bc,
    const float* __restrict__ Wb, const float* __restrict__ bb,
    const float* __restrict__ Wd, const float* __restrict__ bd)
{
    __shared__ float4 sWa[1024], sWc[1024], sWb[1024], sWd[1024];
    __shared__ __align__(16) float sh_h[NPB][64];
    __shared__ __align__(16) float sh_g[NPB][64];

    const int tid = threadIdx.x;
    for (int i = tid; i < 1024; i += 512) {
        sWa[i] = ((const float4*)Wa)[i];
        sWc[i] = ((const float4*)Wc)[i];
        sWb[i] = ((const float4*)Wb)[i];
        sWd[i] = ((const float4*)Wd)[i];
    }

    const int lane = tid & 63;
    const int wave = tid >> 6;
    const int nj   = lane >> 4;
    const int fg   = lane & 15;
    const int slot = wave * 4 + nj;

    const float4 bia  = ((const float4*)ba)[fg];
    const float4 bic  = ((const float4*)bc)[fg];
    const float4 bib  = ((const float4*)bb)[fg];
    const float4 bid_ = ((const float4*)bd)[fg];

    const int ngroups = (NN + NPB - 1) / NPB;
    for (int g = blockIdx.x; g < ngroups; g += gridDim.x) {
        const int node = g * NPB + slot;
        float4 h4 = make_float4(0.f, 0.f, 0.f, 0.f);
        float4 a4 = make_float4(0.f, 0.f, 0.f, 0.f);
        if (node < NN) {
            h4 = *(const float4*)(h_in + node * 64 + fg * 4);
            int e = rs[node];
            const int ee = rs[node + 1];
            for (; e < ee; ++e) {
                const int sN = csr[e];
                const float4 v = *(const float4*)(h_in + sN * 64 + fg * 4);
                a4.x += v.x; a4.y += v.y; a4.z += v.z; a4.w += v.w;
            }
        }
        __syncthreads();
        *(float4*)(&sh_h[slot][fg * 4]) = h4;
        *(float4*)(&sh_g[slot][fg * 4]) = a4;
        __syncthreads();

        float4 accA = {0.f,0.f,0.f,0.f}, accC = {0.f,0.f,0.f,0.f};
        float4 accB = {0.f,0.f,0.f,0.f}, accD = {0.f,0.f,0.f,0.f};
        #pragma unroll 8
        for (int k = 0; k < 64; ++k) {
            const float hk = sh_h[slot][k];
            const float gk = sh_g[slot][k];
            const float4 wa = sWa[k * 16 + fg];
            const float4 wc = sWc[k * 16 + fg];
            const float4 wb = sWb[k * 16 + fg];
            const float4 wd = sWd[k * 16 + fg];
            accA.x = fmaf(hk, wa.x, accA.x); accA.y = fmaf(hk, wa.y, accA.y);
            accA.z = fmaf(hk, wa.z, accA.z); accA.w = fmaf(hk, wa.w, accA.w);
            accC.x = fmaf(gk, wc.x, accC.x); accC.y = fmaf(gk, wc.y, accC.y);
            accC.z = fmaf(gk, wc.z, accC.z); accC.w = fmaf(gk, wc.w, accC.w);
            accB.x = fmaf(hk, wb.x, accB.x); accB.y = fmaf(hk, wb.y, accB.y);
            accB.z = fmaf(hk, wb.z, accB.z); accB.w = fmaf(hk, wb.w, accB.w);
            accD.x = fmaf(hk, wd.x, accD.x); accD.y = fmaf(hk, wd.y, accD.y);
            accD.z = fmaf(hk, wd.z, accD.z); accD.w = fmaf(hk, wd.w, accD.w);
        }
        if (node < NN) {
            float4 o;
            o.x = fmaxf((accA.x + bia.x) + (accC.x + bic.x) + (accB.x + bib.x) * (accD.x + bid_.x), 0.f);
            o.y = fmaxf((accA.y + bia.y) + (accC.y + bic.y) + (accB.y + bib.y) * (accD.y + bid_.y), 0.f);
            o.z = fmaxf((accA.z + bia.z) + (accC.z + bic.z) + (accB.z + bib.z) * (accD.z + bid_.z), 0.f);
            o.w = fmaxf((accA.w + bia.w) + (accC.w + bib.w) * 0.f + (accB.w + bib.w) * (accD.w + bid_.w) + (accC.w + bic.w), 0.f);
            // (rewrite w-component cleanly)
            o.w = fmaxf((accA.w + bia.w) + (accC.w + bic.w) + (accB.w + bib.w) * (accD.w + bid_.w), 0.f);
            *(float4*)(h_out + node * 64 + fg * 4) = o;
        }
    }
}

// ---------------- pool + MLP ----------------
__global__ __launch_bounds__(256) void pool_mlp_kernel(
    const float* __restrict__ h, const int* __restrict__ batch,
    const float* __restrict__ w1, const float* __restrict__ b1,
    const float* __restrict__ w2, const float* __restrict__ b2,
    float* __restrict__ out)
{
    const int g = blockIdx.x;
    const int t = threadIdx.x;
    int lo = 0, hi = NN;
    while (lo < hi) { int m = (lo + hi) >> 1; if (batch[m] < g) lo = m + 1; else hi = m; }
    const int start = lo;
    hi = NN;
    while (lo < hi) { int m = (lo + hi) >> 1; if (batch[m] < g + 1) lo = m + 1; else hi = m; }
    const int end = lo;

    const int f = t & 63, wsub = t >> 6;
    float sum = 0.f;
    for (int n = start + wsub; n < end; n += 4) sum += h[n * 64 + f];
    __shared__ float red[4][64];
    red[wsub][f] = sum;
    __syncthreads();
    __shared__ float pooled[64];
    if (t < 64) {
        float tot = red[0][t] + red[1][t] + red[2][t] + red[3][t];
        pooled[t] = tot / fmaxf((float)(end - start), 1.f);
    }
    __syncthreads();
    __shared__ float y10[10];
    if (t < 10) {
        float acc = b1[t];
        for (int k = 0; k < 64; ++k) acc = fmaf(pooled[k], w1[k * 10 + t], acc);
        y10[t] = acc;
    }
    __syncthreads();
    if (t == 0) {
        float acc = b2[0];
        for (int j = 0; j < 10; ++j) acc = fmaf(y10[j], w2[j], acc);
        out[g] = acc;
    }
}

extern "C" void kernel_launch(void* const* d_in, const int* in_sizes, int n_in,
                              void* d_out, int out_size, void* d_ws, size_t ws_size,
                              hipStream_t stream) {
    const float* x    = (const float*)d_in[0];
    const int* ei     = (const int*)d_in[1];
    const int* batch  = (const int*)d_in[2];
    const int* src    = ei;
    const int* dstv   = ei + NE;

    // workspace layout (bytes):
    //   hA: [0, 25.6M)  hB: [25.6M, 51.2M)  csr: [51.2M, 57.6M)  rs: [57.6M, +400004)
    //   cnt aliases hB+0, cursor aliases hB+512K, bsum aliases hB+1.5M (dead before hB written)
    char* ws    = (char*)d_ws;
    float* hA   = (float*)(ws);
    float* hB   = (float*)(ws + 25600000);
    int* csr    = (int*)(ws + 51200000);
    int* rs     = (int*)(ws + 57600000);
    int* cnt    = (int*)hB;
    int* cursor = (int*)(ws + 25600000 + 524288);
    int* bsum   = (int*)(ws + 25600000 + 1572864);

    hipMemsetAsync(cnt, 0, NN * sizeof(int), stream);
    hist_kernel<<<(NE + 255) / 256, 256, 0, stream>>>(dstv, cnt);
    scan1_kernel<<<SNBLK, 256, 0, stream>>>(cnt, rs, bsum);
    scan2_kernel<<<1, 128, 0, stream>>>(bsum, rs);
    scan3_kernel<<<SNBLK, 256, 0, stream>>>(rs, bsum, cursor);
    fill_kernel<<<(NE + 255) / 256, 256, 0, stream>>>(src, dstv, cursor, csr);

    auto f = [&](int i) { return (const float*)d_in[i]; };
    layer_kernel<<<LAYER_GRID, 512, 0, stream>>>(x, hA, csr, rs,
        f(5), f(6), f(3), f(4), f(7), f(8), f(9), f(10));
    layer_kernel<<<LAYER_GRID, 512, 0, stream>>>(hA, hB, csr, rs,
        f(13), f(14), f(11), f(12), f(15), f(16), f(17), f(18));
    layer_kernel<<<LAYER_GRID, 512, 0, stream>>>(hB, hA, csr, rs,
        f(21), f(22), f(19), f(20), f(23), f(24), f(25), f(26));

    pool_mlp_kernel<<<NG, 256, 0, stream>>>(hA, batch,
        f(27), f(28), f(29), f(30), (float*)d_out);
}

// Round 3
// 519.766 us; speedup vs baseline: 1.7485x; 1.3259x over previous
//
#include <hip/hip_runtime.h>

#define NN 100000
#define NE 1600000
#define NG 256
#define NPB 32            // nodes per block-pass in layer kernel
#define LAYER_GRID 512
#define SCHUNK 1024
#define SNBLK ((NN + SCHUNK - 1) / SCHUNK)   // 98

__device__ __forceinline__ void acc4(float4& a, const float4& v) {
    a.x += v.x; a.y += v.y; a.z += v.z; a.w += v.w;
}

// ---------------- CSR build (by dst) ----------------
__global__ __launch_bounds__(256) void hist_kernel(const int* __restrict__ dst,
                                                   int* __restrict__ cnt) {
    int i = blockIdx.x * 256 + threadIdx.x;
    if (i < NE) atomicAdd(&cnt[dst[i]], 1);
}

// Pass 1: per-block (1024 counts) exclusive scan -> rs, block total -> bsum[b]
__global__ __launch_bounds__(256) void scan1_kernel(const int* __restrict__ cnt,
                                                    int* __restrict__ rs,
                                                    int* __restrict__ bsum) {
    __shared__ int s[256];
    const int b = blockIdx.x, t = threadIdx.x;
    const int idx = b * SCHUNK + t * 4;
    int4 v = {0, 0, 0, 0};
    if (idx + 3 < NN) v = *(const int4*)(cnt + idx);
    else {
        if (idx + 0 < NN) v.x = cnt[idx + 0];
        if (idx + 1 < NN) v.y = cnt[idx + 1];
        if (idx + 2 < NN) v.z = cnt[idx + 2];
        if (idx + 3 < NN) v.w = cnt[idx + 3];
    }
    s[t] = v.x + v.y + v.z + v.w;
    __syncthreads();
    for (int off = 1; off < 256; off <<= 1) {
        int u = (t >= off) ? s[t - off] : 0;
        __syncthreads();
        s[t] += u;
        __syncthreads();
    }
    int r0 = (t == 0) ? 0 : s[t - 1];
    int r1 = r0 + v.x, r2 = r1 + v.y, r3 = r2 + v.z;
    if (idx + 0 < NN) rs[idx + 0] = r0;
    if (idx + 1 < NN) rs[idx + 1] = r1;
    if (idx + 2 < NN) rs[idx + 2] = r2;
    if (idx + 3 < NN) rs[idx + 3] = r3;
    if (t == 255) bsum[b] = s[255];
}

// Pass 2: exclusive scan of the SNBLK block sums; grand total -> rs[NN]
__global__ __launch_bounds__(128) void scan2_kernel(int* __restrict__ bsum,
                                                    int* __restrict__ rs) {
    __shared__ int s[128];
    const int t = threadIdx.x;
    int v = (t < SNBLK) ? bsum[t] : 0;
    s[t] = v;
    __syncthreads();
    for (int off = 1; off < 128; off <<= 1) {
        int u = (t >= off) ? s[t - off] : 0;
        __syncthreads();
        s[t] += u;
        __syncthreads();
    }
    if (t < SNBLK) bsum[t] = (t == 0) ? 0 : s[t - 1];
    if (t == 127) rs[NN] = s[127];
}

// Pass 3: add block offsets; mirror into cursor
__global__ __launch_bounds__(256) void scan3_kernel(int* __restrict__ rs,
                                                    const int* __restrict__ bsum,
                                                    int* __restrict__ cursor) {
    const int b = blockIdx.x, t = threadIdx.x;
    const int off = bsum[b];
    const int idx = b * SCHUNK + t * 4;
    if (idx + 3 < NN) {
        int4 v = *(const int4*)(rs + idx);
        v.x += off; v.y += off; v.z += off; v.w += off;
        *(int4*)(rs + idx) = v;
        *(int4*)(cursor + idx) = v;
    } else {
        for (int j = 0; j < 4; ++j)
            if (idx + j < NN) { int v = rs[idx + j] + off; rs[idx + j] = v; cursor[idx + j] = v; }
    }
}

__global__ __launch_bounds__(256) void fill_kernel(const int* __restrict__ src,
                                                   const int* __restrict__ dst,
                                                   int* __restrict__ cursor,
                                                   int* __restrict__ csr) {
    int i = blockIdx.x * 256 + threadIdx.x;
    if (i < NE) {
        int pos = atomicAdd(&cursor[dst[i]], 1);
        csr[pos] = src[i];
    }
}

// ---------------- fused GNN layer ----------------
// out = relu( h@Wa+ba  +  agg(h)@Wc+bc  +  (h@Wb+bb)*(h@Wd+bd) )
// Gather is 8-wide unrolled with masking: 8 independent row loads in flight
// per wave per iteration (latency hiding); csr reads are contiguous.
__global__ __launch_bounds__(512, 4) void layer_kernel(
    const float* __restrict__ h_in, float* __restrict__ h_out,
    const int* __restrict__ csr, const int* __restrict__ rs,
    const float* __restrict__ Wa, const float* __restrict__ ba,
    const float* __restrict__ Wc, const float* __restrict__ bc,
    const float* __restrict__ Wb, const float* __restrict__ bb,
    const float* __restrict__ Wd, const float* __restrict__ bd)
{
    __shared__ float4 sWa[1024], sWc[1024], sWb[1024], sWd[1024];
    __shared__ __align__(16) float sh_h[NPB][64];
    __shared__ __align__(16) float sh_g[NPB][64];

    const int tid = threadIdx.x;
    for (int i = tid; i < 1024; i += 512) {
        sWa[i] = ((const float4*)Wa)[i];
        sWc[i] = ((const float4*)Wc)[i];
        sWb[i] = ((const float4*)Wb)[i];
        sWd[i] = ((const float4*)Wd)[i];
    }

    const int lane = tid & 63;
    const int wave = tid >> 6;
    const int nj   = lane >> 4;
    const int fg   = lane & 15;
    const int slot = wave * 4 + nj;

    const float4 bia  = ((const float4*)ba)[fg];
    const float4 bic  = ((const float4*)bc)[fg];
    const float4 bib  = ((const float4*)bb)[fg];
    const float4 bid_ = ((const float4*)bd)[fg];

    const int ngroups = (NN + NPB - 1) / NPB;
    for (int g = blockIdx.x; g < ngroups; g += gridDim.x) {
        const int node = g * NPB + slot;
        float4 h4 = make_float4(0.f, 0.f, 0.f, 0.f);
        float4 a4 = make_float4(0.f, 0.f, 0.f, 0.f);
        if (node < NN) {
            h4 = *(const float4*)(h_in + node * 64 + fg * 4);
            int e = rs[node];
            const int ee = rs[node + 1];
            for (; e < ee; e += 8) {
                const int rem = ee - e;
                const int s0 = csr[e];
                const int s1 = rem > 1 ? csr[e + 1] : s0;
                const int s2 = rem > 2 ? csr[e + 2] : s0;
                const int s3 = rem > 3 ? csr[e + 3] : s0;
                const int s4 = rem > 4 ? csr[e + 4] : s0;
                const int s5 = rem > 5 ? csr[e + 5] : s0;
                const int s6 = rem > 6 ? csr[e + 6] : s0;
                const int s7 = rem > 7 ? csr[e + 7] : s0;
                const float4 v0 = *(const float4*)(h_in + s0 * 64 + fg * 4);
                const float4 v1 = *(const float4*)(h_in + s1 * 64 + fg * 4);
                const float4 v2 = *(const float4*)(h_in + s2 * 64 + fg * 4);
                const float4 v3 = *(const float4*)(h_in + s3 * 64 + fg * 4);
                const float4 v4 = *(const float4*)(h_in + s4 * 64 + fg * 4);
                const float4 v5 = *(const float4*)(h_in + s5 * 64 + fg * 4);
                const float4 v6 = *(const float4*)(h_in + s6 * 64 + fg * 4);
                const float4 v7 = *(const float4*)(h_in + s7 * 64 + fg * 4);
                acc4(a4, v0);
                if (rem > 1) acc4(a4, v1);
                if (rem > 2) acc4(a4, v2);
                if (rem > 3) acc4(a4, v3);
                if (rem > 4) acc4(a4, v4);
                if (rem > 5) acc4(a4, v5);
                if (rem > 6) acc4(a4, v6);
                if (rem > 7) acc4(a4, v7);
            }
        }
        __syncthreads();
        *(float4*)(&sh_h[slot][fg * 4]) = h4;
        *(float4*)(&sh_g[slot][fg * 4]) = a4;
        __syncthreads();

        float4 accA = {0.f,0.f,0.f,0.f}, accC = {0.f,0.f,0.f,0.f};
        float4 accB = {0.f,0.f,0.f,0.f}, accD = {0.f,0.f,0.f,0.f};
        #pragma unroll 8
        for (int k = 0; k < 64; ++k) {
            const float hk = sh_h[slot][k];
            const float gk = sh_g[slot][k];
            const float4 wa = sWa[k * 16 + fg];
            const float4 wc = sWc[k * 16 + fg];
            const float4 wb = sWb[k * 16 + fg];
            const float4 wd = sWd[k * 16 + fg];
            accA.x = fmaf(hk, wa.x, accA.x); accA.y = fmaf(hk, wa.y, accA.y);
            accA.z = fmaf(hk, wa.z, accA.z); accA.w = fmaf(hk, wa.w, accA.w);
            accC.x = fmaf(gk, wc.x, accC.x); accC.y = fmaf(gk, wc.y, accC.y);
            accC.z = fmaf(gk, wc.z, accC.z); accC.w = fmaf(gk, wc.w, accC.w);
            accB.x = fmaf(hk, wb.x, accB.x); accB.y = fmaf(hk, wb.y, accB.y);
            accB.z = fmaf(hk, wb.z, accB.z); accB.w = fmaf(hk, wb.w, accB.w);
            accD.x = fmaf(hk, wd.x, accD.x); accD.y = fmaf(hk, wd.y, accD.y);
            accD.z = fmaf(hk, wd.z, accD.z); accD.w = fmaf(hk, wd.w, accD.w);
        }
        if (node < NN) {
            float4 o;
            o.x = fmaxf((accA.x + bia.x) + (accC.x + bic.x) + (accB.x + bib.x) * (accD.x + bid_.x), 0.f);
            o.y = fmaxf((accA.y + bia.y) + (accC.y + bic.y) + (accB.y + bib.y) * (accD.y + bid_.y), 0.f);
            o.z = fmaxf((accA.z + bia.z) + (accC.z + bic.z) + (accB.z + bib.z) * (accD.z + bid_.z), 0.f);
            o.w = fmaxf((accA.w + bia.w) + (accC.w + bic.w) + (accB.w + bib.w) * (accD.w + bid_.w), 0.f);
            *(float4*)(h_out + node * 64 + fg * 4) = o;
        }
    }
}

// ---------------- pool + MLP ----------------
__global__ __launch_bounds__(256) void pool_mlp_kernel(
    const float* __restrict__ h, const int* __restrict__ batch,
    const float* __restrict__ w1, const float* __restrict__ b1,
    const float* __restrict__ w2, const float* __restrict__ b2,
    float* __restrict__ out)
{
    const int g = blockIdx.x;
    const int t = threadIdx.x;
    int lo = 0, hi = NN;
    while (lo < hi) { int m = (lo + hi) >> 1; if (batch[m] < g) lo = m + 1; else hi = m; }
    const int start = lo;
    hi = NN;
    while (lo < hi) { int m = (lo + hi) >> 1; if (batch[m] < g + 1) lo = m + 1; else hi = m; }
    const int end = lo;

    const int f = t & 63, wsub = t >> 6;
    float sum = 0.f;
    for (int n = start + wsub; n < end; n += 4) sum += h[n * 64 + f];
    __shared__ float red[4][64];
    red[wsub][f] = sum;
    __syncthreads();
    __shared__ float pooled[64];
    if (t < 64) {
        float tot = red[0][t] + red[1][t] + red[2][t] + red[3][t];
        pooled[t] = tot / fmaxf((float)(end - start), 1.f);
    }
    __syncthreads();
    __shared__ float y10[10];
    if (t < 10) {
        float acc = b1[t];
        for (int k = 0; k < 64; ++k) acc = fmaf(pooled[k], w1[k * 10 + t], acc);
        y10[t] = acc;
    }
    __syncthreads();
    if (t == 0) {
        float acc = b2[0];
        for (int j = 0; j < 10; ++j) acc = fmaf(y10[j], w2[j], acc);
        out[g] = acc;
    }
}

extern "C" void kernel_launch(void* const* d_in, const int* in_sizes, int n_in,
                              void* d_out, int out_size, void* d_ws, size_t ws_size,
                              hipStream_t stream) {
    const float* x    = (const float*)d_in[0];
    const int* ei     = (const int*)d_in[1];
    const int* batch  = (const int*)d_in[2];
    const int* src    = ei;
    const int* dstv   = ei + NE;

    // workspace layout (bytes):
    //   hA: [0, 25.6M)  hB: [25.6M, 51.2M)  csr: [51.2M, 57.6M)  rs: [57.6M, +400004)
    //   cnt aliases hB+0, cursor aliases hB+512K, bsum aliases hB+1.5M (dead before hB written)
    char* ws    = (char*)d_ws;
    float* hA   = (float*)(ws);
    float* hB   = (float*)(ws + 25600000);
    int* csr    = (int*)(ws + 51200000);
    int* rs     = (int*)(ws + 57600000);
    int* cnt    = (int*)hB;
    int* cursor = (int*)(ws + 25600000 + 524288);
    int* bsum   = (int*)(ws + 25600000 + 1572864);

    hipMemsetAsync(cnt, 0, NN * sizeof(int), stream);
    hist_kernel<<<(NE + 255) / 256, 256, 0, stream>>>(dstv, cnt);
    scan1_kernel<<<SNBLK, 256, 0, stream>>>(cnt, rs, bsum);
    scan2_kernel<<<1, 128, 0, stream>>>(bsum, rs);
    scan3_kernel<<<SNBLK, 256, 0, stream>>>(rs, bsum, cursor);
    fill_kernel<<<(NE + 255) / 256, 256, 0, stream>>>(src, dstv, cursor, csr);

    auto f = [&](int i) { return (const float*)d_in[i]; };
    layer_kernel<<<LAYER_GRID, 512, 0, stream>>>(x, hA, csr, rs,
        f(5), f(6), f(3), f(4), f(7), f(8), f(9), f(10));
    layer_kernel<<<LAYER_GRID, 512, 0, stream>>>(hA, hB, csr, rs,
        f(13), f(14), f(11), f(12), f(15), f(16), f(17), f(18));
    layer_kernel<<<LAYER_GRID, 512, 0, stream>>>(hB, hA, csr, rs,
        f(21), f(22), f(19), f(20), f(23), f(24), f(25), f(26));

    pool_mlp_kernel<<<NG, 256, 0, stream>>>(hA, batch,
        f(27), f(28), f(29), f(30), (float*)d_out);
}

// Round 4
// 366.397 us; speedup vs baseline: 2.4804x; 1.4186x over previous
//
#include <hip/hip_runtime.h>

#define NN 100000
#define NE 1600000
#define NG 256
#define NPB 32            // nodes per block-pass in layer kernel
#define LAYER_GRID 512

// binned CSR build
#define BSH 9                         // bucket = dst >> 9 (512 nodes/bucket)
#define NBKT ((NN + 511) / 512)       // 196
#define CAP 9216                      // per-bucket capacity (mean 8163, +11.7 sigma)
#define TILE_A 4096
#define NBLK_A ((NE + TILE_A - 1) / TILE_A)   // 391

__device__ __forceinline__ void acc4(float4& a, const float4& v) {
    a.x += v.x; a.y += v.y; a.z += v.z; a.w += v.w;
}

// ---------------- binned CSR build ----------------
__global__ __launch_bounds__(256) void initcur_kernel(int* __restrict__ gcur) {
    int t = threadIdx.x;
    if (t < NBKT) gcur[t] = t * CAP;
}

// Pass A: partition edges into NBKT buckets (packed u32 = src<<9 | (dst&511)),
// LDS-reordered so global writes are contiguous runs per (block,bucket).
__global__ __launch_bounds__(256) void binA_kernel(const int* __restrict__ src,
                                                   const int* __restrict__ dst,
                                                   int* __restrict__ gcur,
                                                   unsigned int* __restrict__ binned)
{
    __shared__ int hist[NBKT];
    __shared__ int cnt2[NBKT];
    __shared__ int lexcl[NBKT];
    __shared__ int base[NBKT];
    __shared__ int s[256];
    __shared__ unsigned int buf[TILE_A];
    __shared__ unsigned char bkt8[TILE_A];

    const int t = threadIdx.x;
    const int e0 = blockIdx.x * TILE_A;
    const int nedge = min(TILE_A, NE - e0);

    if (t < NBKT) { hist[t] = 0; cnt2[t] = 0; }
    __syncthreads();

    // 1: bucket histogram
    for (int j = t; j < nedge; j += 256)
        atomicAdd(&hist[dst[e0 + j] >> BSH], 1);
    __syncthreads();

    // 2: exclusive scan of hist
    s[t] = (t < NBKT) ? hist[t] : 0;
    __syncthreads();
    for (int off = 1; off < 256; off <<= 1) {
        int u = (t >= off) ? s[t - off] : 0;
        __syncthreads();
        s[t] += u;
        __syncthreads();
    }
    if (t < NBKT) {
        lexcl[t] = s[t] - hist[t];
        if (hist[t] > 0) base[t] = atomicAdd(&gcur[t], hist[t]);   // reserve
    }
    __syncthreads();

    // 3: rank + LDS reorder
    for (int j = t; j < nedge; j += 256) {
        const int d = dst[e0 + j];
        const int sv = src[e0 + j];
        const int b = d >> BSH;
        const int r = atomicAdd(&cnt2[b], 1);
        const int idx = lexcl[b] + r;
        buf[idx] = ((unsigned int)sv << BSH) | (unsigned int)(d & 511);
        bkt8[idx] = (unsigned char)b;
    }
    __syncthreads();

    // 4: bucket-grouped global write (contiguous run per bucket)
    for (int j = t; j < nedge; j += 256) {
        const int b = bkt8[j];
        binned[base[b] + (j - lexcl[b])] = buf[j];
    }
}

// exclusive scan of actual bucket sizes -> bucket base offsets in final csr
__global__ __launch_bounds__(256) void bscan_kernel(const int* __restrict__ gcur,
                                                    int* __restrict__ bbase,
                                                    int* __restrict__ rs)
{
    __shared__ int s[256];
    const int t = threadIdx.x;
    const int sz = (t < NBKT) ? (gcur[t] - t * CAP) : 0;
    s[t] = sz;
    __syncthreads();
    for (int off = 1; off < 256; off <<= 1) {
        int u = (t >= off) ? s[t - off] : 0;
        __syncthreads();
        s[t] += u;
        __syncthreads();
    }
    if (t < NBKT) bbase[t] = s[t] - sz;
    if (t == 0) rs[NN] = NE;
}

// Pass B: per-bucket counting sort -> dense csr + rs
__global__ __launch_bounds__(256) void binB_kernel(const unsigned int* __restrict__ binned,
                                                   const int* __restrict__ gcur,
                                                   const int* __restrict__ bbase,
                                                   int* __restrict__ csr,
                                                   int* __restrict__ rs)
{
    __shared__ int cnt[512];
    __shared__ int excl[512];
    __shared__ int cnt2[512];
    __shared__ int psum[256];
    __shared__ unsigned int buf[CAP];

    const int b = blockIdx.x;
    const int t = threadIdx.x;
    const int sz = gcur[b] - b * CAP;
    const int gb = bbase[b];
    const unsigned int* bp = binned + b * CAP;

    cnt[t] = 0; cnt[t + 256] = 0;
    cnt2[t] = 0; cnt2[t + 256] = 0;
    __syncthreads();

    for (int j = t; j < sz; j += 256) {
        const unsigned int v = bp[j];
        buf[j] = v;
        atomicAdd(&cnt[v & 511], 1);
    }
    __syncthreads();

    // exclusive scan over 512 node-counts (pairwise + 256-scan)
    const int c0 = cnt[2 * t], c1 = cnt[2 * t + 1];
    psum[t] = c0 + c1;
    __syncthreads();
    for (int off = 1; off < 256; off <<= 1) {
        int u = (t >= off) ? psum[t - off] : 0;
        __syncthreads();
        psum[t] += u;
        __syncthreads();
    }
    const int pe = psum[t] - (c0 + c1);
    excl[2 * t] = pe;
    excl[2 * t + 1] = pe + c0;
    __syncthreads();

    // rs for this bucket's nodes
    const int node0 = b << BSH;
    for (int l = t; l < 512; l += 256) {
        const int node = node0 + l;
        if (node < NN) rs[node] = gb + excl[l];
    }

    // scatter src into dense csr (hot 32KB region, single-block owner)
    for (int j = t; j < sz; j += 256) {
        const unsigned int v = buf[j];
        const int l = v & 511;
        const int r = atomicAdd(&cnt2[l], 1);
        csr[gb + excl[l] + r] = (int)(v >> BSH);
    }
}

// ---------------- fused GNN layer ----------------
// out = relu( h@Wa+ba  +  agg(h)@Wc+bc  +  (h@Wb+bb)*(h@Wd+bd) )
__global__ __launch_bounds__(512, 4) void layer_kernel(
    const float* __restrict__ h_in, float* __restrict__ h_out,
    const int* __restrict__ csr, const int* __restrict__ rs,
    const float* __restrict__ Wa, const float* __restrict__ ba,
    const float* __restrict__ Wc, const float* __restrict__ bc,
    const float* __restrict__ Wb, const float* __restrict__ bb,
    const float* __restrict__ Wd, const float* __restrict__ bd)
{
    __shared__ float4 sWa[1024], sWc[1024], sWb[1024], sWd[1024];
    __shared__ __align__(16) float sh_h[NPB][64];
    __shared__ __align__(16) float sh_g[NPB][64];

    const int tid = threadIdx.x;
    for (int i = tid; i < 1024; i += 512) {
        sWa[i] = ((const float4*)Wa)[i];
        sWc[i] = ((const float4*)Wc)[i];
        sWb[i] = ((const float4*)Wb)[i];
        sWd[i] = ((const float4*)Wd)[i];
    }

    const int lane = tid & 63;
    const int wave = tid >> 6;
    const int nj   = lane >> 4;
    const int fg   = lane & 15;
    const int slot = wave * 4 + nj;

    const float4 bia  = ((const float4*)ba)[fg];
    const float4 bic  = ((const float4*)bc)[fg];
    const float4 bib  = ((const float4*)bb)[fg];
    const float4 bid_ = ((const float4*)bd)[fg];

    const int ngroups = (NN + NPB - 1) / NPB;
    for (int g = blockIdx.x; g < ngroups; g += gridDim.x) {
        const int node = g * NPB + slot;
        float4 h4 = make_float4(0.f, 0.f, 0.f, 0.f);
        float4 a4 = make_float4(0.f, 0.f, 0.f, 0.f);
        if (node < NN) {
            h4 = *(const float4*)(h_in + node * 64 + fg * 4);
            int e = rs[node];
            const int ee = rs[node + 1];
            for (; e < ee; e += 8) {
                const int rem = ee - e;
                const int s0 = csr[e];
                const int s1 = rem > 1 ? csr[e + 1] : s0;
                const int s2 = rem > 2 ? csr[e + 2] : s0;
                const int s3 = rem > 3 ? csr[e + 3] : s0;
                const int s4 = rem > 4 ? csr[e + 4] : s0;
                const int s5 = rem > 5 ? csr[e + 5] : s0;
                const int s6 = rem > 6 ? csr[e + 6] : s0;
                const int s7 = rem > 7 ? csr[e + 7] : s0;
                const float4 v0 = *(const float4*)(h_in + s0 * 64 + fg * 4);
                const float4 v1 = *(const float4*)(h_in + s1 * 64 + fg * 4);
                const float4 v2 = *(const float4*)(h_in + s2 * 64 + fg * 4);
                const float4 v3 = *(const float4*)(h_in + s3 * 64 + fg * 4);
                const float4 v4 = *(const float4*)(h_in + s4 * 64 + fg * 4);
                const float4 v5 = *(const float4*)(h_in + s5 * 64 + fg * 4);
                const float4 v6 = *(const float4*)(h_in + s6 * 64 + fg * 4);
                const float4 v7 = *(const float4*)(h_in + s7 * 64 + fg * 4);
                acc4(a4, v0);
                if (rem > 1) acc4(a4, v1);
                if (rem > 2) acc4(a4, v2);
                if (rem > 3) acc4(a4, v3);
                if (rem > 4) acc4(a4, v4);
                if (rem > 5) acc4(a4, v5);
                if (rem > 6) acc4(a4, v6);
                if (rem > 7) acc4(a4, v7);
            }
        }
        __syncthreads();
        *(float4*)(&sh_h[slot][fg * 4]) = h4;
        *(float4*)(&sh_g[slot][fg * 4]) = a4;
        __syncthreads();

        float4 accA = {0.f,0.f,0.f,0.f}, accC = {0.f,0.f,0.f,0.f};
        float4 accB = {0.f,0.f,0.f,0.f}, accD = {0.f,0.f,0.f,0.f};
        #pragma unroll 8
        for (int k = 0; k < 64; ++k) {
            const float hk = sh_h[slot][k];
            const float gk = sh_g[slot][k];
            const float4 wa = sWa[k * 16 + fg];
            const float4 wc = sWc[k * 16 + fg];
            const float4 wb = sWb[k * 16 + fg];
            const float4 wd = sWd[k * 16 + fg];
            accA.x = fmaf(hk, wa.x, accA.x); accA.y = fmaf(hk, wa.y, accA.y);
            accA.z = fmaf(hk, wa.z, accA.z); accA.w = fmaf(hk, wa.w, accA.w);
            accC.x = fmaf(gk, wc.x, accC.x); accC.y = fmaf(gk, wc.y, accC.y);
            accC.z = fmaf(gk, wc.z, accC.z); accC.w = fmaf(gk, wc.w, accC.w);
            accB.x = fmaf(hk, wb.x, accB.x); accB.y = fmaf(hk, wb.y, accB.y);
            accB.z = fmaf(hk, wb.z, accB.z); accB.w = fmaf(hk, wb.w, accB.w);
            accD.x = fmaf(hk, wd.x, accD.x); accD.y = fmaf(hk, wd.y, accD.y);
            accD.z = fmaf(hk, wd.z, accD.z); accD.w = fmaf(hk, wd.w, accD.w);
        }
        if (node < NN) {
            float4 o;
            o.x = fmaxf((accA.x + bia.x) + (accC.x + bic.x) + (accB.x + bib.x) * (accD.x + bid_.x), 0.f);
            o.y = fmaxf((accA.y + bia.y) + (accC.y + bic.y) + (accB.y + bib.y) * (accD.y + bid_.y), 0.f);
            o.z = fmaxf((accA.z + bia.z) + (accC.z + bic.z) + (accB.z + bib.z) * (accD.z + bid_.z), 0.f);
            o.w = fmaxf((accA.w + bia.w) + (accC.w + bic.w) + (accB.w + bib.w) * (accD.w + bid_.w), 0.f);
            *(float4*)(h_out + node * 64 + fg * 4) = o;
        }
    }
}

// ---------------- pool + MLP ----------------
__global__ __launch_bounds__(256) void pool_mlp_kernel(
    const float* __restrict__ h, const int* __restrict__ batch,
    const float* __restrict__ w1, const float* __restrict__ b1,
    const float* __restrict__ w2, const float* __restrict__ b2,
    float* __restrict__ out)
{
    const int g = blockIdx.x;
    const int t = threadIdx.x;
    int lo = 0, hi = NN;
    while (lo < hi) { int m = (lo + hi) >> 1; if (batch[m] < g) lo = m + 1; else hi = m; }
    const int start = lo;
    hi = NN;
    while (lo < hi) { int m = (lo + hi) >> 1; if (batch[m] < g + 1) lo = m + 1; else hi = m; }
    const int end = lo;

    const int f = t & 63, wsub = t >> 6;
    float sum = 0.f;
    for (int n = start + wsub; n < end; n += 4) sum += h[n * 64 + f];
    __shared__ float red[4][64];
    red[wsub][f] = sum;
    __syncthreads();
    __shared__ float pooled[64];
    if (t < 64) {
        float tot = red[0][t] + red[1][t] + red[2][t] + red[3][t];
        pooled[t] = tot / fmaxf((float)(end - start), 1.f);
    }
    __syncthreads();
    __shared__ float y10[10];
    if (t < 10) {
        float acc = b1[t];
        for (int k = 0; k < 64; ++k) acc = fmaf(pooled[k], w1[k * 10 + t], acc);
        y10[t] = acc;
    }
    __syncthreads();
    if (t == 0) {
        float acc = b2[0];
        for (int j = 0; j < 10; ++j) acc = fmaf(y10[j], w2[j], acc);
        out[g] = acc;
    }
}

extern "C" void kernel_launch(void* const* d_in, const int* in_sizes, int n_in,
                              void* d_out, int out_size, void* d_ws, size_t ws_size,
                              hipStream_t stream) {
    const float* x    = (const float*)d_in[0];
    const int* ei     = (const int*)d_in[1];
    const int* batch  = (const int*)d_in[2];
    const int* src    = ei;
    const int* dstv   = ei + NE;

    // workspace layout (bytes):
    //   hA:  [0, 25.6M)
    //   hB:  [25.6M, 51.2M)   -- gcur/bbase/binned alias here (dead before layer-2 writes hB)
    //   csr: [51.2M, 57.6M)
    //   rs:  [57.6M, +400004)
    char* ws     = (char*)d_ws;
    float* hA    = (float*)(ws);
    float* hB    = (float*)(ws + 25600000);
    int* csr     = (int*)(ws + 51200000);
    int* rs      = (int*)(ws + 57600000);
    int* gcur    = (int*)(ws + 25600000);
    int* bbase   = (int*)(ws + 25600000 + 1024);
    unsigned int* binned = (unsigned int*)(ws + 25600000 + 2048);   // 7.2MB

    initcur_kernel<<<1, 256, 0, stream>>>(gcur);
    binA_kernel<<<NBLK_A, 256, 0, stream>>>(src, dstv, gcur, binned);
    bscan_kernel<<<1, 256, 0, stream>>>(gcur, bbase, rs);
    binB_kernel<<<NBKT, 256, 0, stream>>>(binned, gcur, bbase, csr, rs);

    auto f = [&](int i) { return (const float*)d_in[i]; };
    layer_kernel<<<LAYER_GRID, 512, 0, stream>>>(x, hA, csr, rs,
        f(5), f(6), f(3), f(4), f(7), f(8), f(9), f(10));
    layer_kernel<<<LAYER_GRID, 512, 0, stream>>>(hA, hB, csr, rs,
        f(13), f(14), f(11), f(12), f(15), f(16), f(17), f(18));
    layer_kernel<<<LAYER_GRID, 512, 0, stream>>>(hB, hA, csr, rs,
        f(21), f(22), f(19), f(20), f(23), f(24), f(25), f(26));

    pool_mlp_kernel<<<NG, 256, 0, stream>>>(hA, batch,
        f(27), f(28), f(29), f(30), (float*)d_out);
}